// Round 18
// baseline (56.103 us; speedup 1.0000x reference)
//
#include <hip/hip_runtime.h>
#include <hip/hip_bf16.h>

// Problem constants
#define TT 2048
#define BB 4
#define CC 512
#define HH 16
#define KK 31
#define PP 15
#define MM (TT*BB)      // 8192 rows
#define NPAD 512        // HK=496 padded to 512 (pad rows of Wl are zero)

typedef __bf16 bf16x8 __attribute__((ext_vector_type(8)));
typedef float f32x4 __attribute__((ext_vector_type(4)));
typedef unsigned short ushort8 __attribute__((ext_vector_type(8)));
typedef unsigned short ushort4v __attribute__((ext_vector_type(4)));

__device__ __forceinline__ float bf2f(unsigned short u) {
    return __uint_as_float(((unsigned int)u) << 16);
}
__device__ __forceinline__ unsigned short f2bf(float f) {
    unsigned int x = __float_as_uint(f);
    x += 0x7fffu + ((x >> 16) & 1u);
    return (unsigned short)(x >> 16);
}

// ---------------------------------------------------------------------------
// single cast dispatch: blocks 0..4095 cast x (1024 elems each);
// blocks 4096..4863 cast W1/Wl/W2 (Wl zero-padded to 512 rows).
// ---------------------------------------------------------------------------
__global__ __launch_bounds__(256) void cast_all(const float* __restrict__ x,
                                                const float* __restrict__ W1,
                                                const float* __restrict__ Wl,
                                                const float* __restrict__ W2,
                                                unsigned short* __restrict__ xb,
                                                unsigned short* __restrict__ W1b,
                                                unsigned short* __restrict__ Wlb,
                                                unsigned short* __restrict__ W2b) {
    const int b = blockIdx.x;
    if (b < 4096) {
        const int i = b * 1024 + threadIdx.x * 4;
        const float4 v = *(const float4*)&x[i];
        ushort4v o = { f2bf(v.x), f2bf(v.y), f2bf(v.z), f2bf(v.w) };
        *(ushort4v*)&xb[i] = o;
        return;
    }
    const int bb = b - 4096;                 // 0..767
    const int i = (bb & 255) * 1024 + threadIdx.x * 4;
    const float* src;
    unsigned short* dst;
    int n_src = 262144;
    if (bb < 256)      { src = W1; dst = W1b; }
    else if (bb < 512) { src = Wl; dst = Wlb; n_src = HH * KK * CC; }
    else               { src = W2; dst = W2b; }
    ushort4v o = {0, 0, 0, 0};
    if (i < n_src) {
        const float4 v = *(const float4*)&src[i];
        o[0] = f2bf(v.x); o[1] = f2bf(v.y); o[2] = f2bf(v.z); o[3] = f2bf(v.w);
    }
    *(ushort4v*)&dst[i] = o;
}

// ---------------------------------------------------------------------------
// bf16 MFMA GEMM-NT, BK=128 / NT=4 (fewer, fatter barrier steps):
// C[m,n] = sum_k A[m,k]*B[n,k] (+bias[n]); K fixed 512 (NT=4 x BK=128).
// 128x64 tile, 512 thr = 8 waves (4m x 2n), wave-tile 32x32, 16 MFMA/step.
// 3-stage LDS = 3 x (32+16) KB = 144 KB -> 1 block/CU, 8 waves (2/SIMD).
// Per iter kt: {vmcnt(6); s_barrier; STAGE(kt+2); compute buf kt%3}.
// STAGE = 6 loads/thread (A: 2048 slots = 4 rounds x 512; B: 1024 = 2 rounds).
// vmcnt(6) = tile kt resident, kt+1's 6 loads stay in flight (never 0 in-loop).
// Swizzle (16 slots/row of 16B): slot' = slot ^ (r&15) -> lanes' slot'%8
// covers each bank-group exactly twice (2-way = free, m136). Both sides.
// Buffer safety: STAGE(kt+2)->buf (kt+2)%3 = (kt-1)%3, issued after barrier
// kt which follows compute(kt-1)'s reads of that buffer.
// ---------------------------------------------------------------------------
#define GBM 128
#define GBN 64
#define GBK 128
#define KC  512
#define NT  4

#define STAGE(kt, buf)                                                                              \
    do {                                                                                            \
        const int k0_ = (kt) * GBK;                                                                 \
        _Pragma("unroll")                                                                           \
        for (int j = 0; j < 4; ++j)                                                                 \
            __builtin_amdgcn_global_load_lds(                                                       \
                (const __attribute__((address_space(1))) void*)(gA[j] + k0_),                       \
                (__attribute__((address_space(3))) void*)(&As[buf][0] + (j * 512 + wv * 64) * 8),   \
                16, 0, 0);                                                                          \
        _Pragma("unroll")                                                                           \
        for (int j = 0; j < 2; ++j)                                                                 \
            __builtin_amdgcn_global_load_lds(                                                       \
                (const __attribute__((address_space(1))) void*)(gB[j] + k0_),                       \
                (__attribute__((address_space(3))) void*)(&Bs[buf][0] + (j * 512 + wv * 64) * 8),   \
                16, 0, 0);                                                                          \
    } while (0)

template<bool OUT_BF16>
__global__ __launch_bounds__(512, 2) void gemm_nt_mfma(const unsigned short* __restrict__ A,
                                                       const unsigned short* __restrict__ B,
                                                       const float* __restrict__ bias,
                                                       void* __restrict__ Cout,
                                                       int N, int nn) {
    __shared__ short As[3][GBM * GBK];   // 3 x 32 KB
    __shared__ short Bs[3][GBN * GBK];   // 3 x 16 KB

    const int tid = threadIdx.x;
    const int l   = tid & 63;
    const int wv  = tid >> 6;      // wave 0..7
    const int wr  = wv >> 1;       // wave row (0..3) -> 32 rows each
    const int wc  = wv & 1;        // wave col (0..1) -> 32 cols each

    // chunked XCD swizzle; consecutive s share A panel in the XCD's L2
    const int s  = (blockIdx.x & 7) * (gridDim.x >> 3) + (blockIdx.x >> 3);
    const int bm = (s / nn) * GBM;
    const int bn = (s % nn) * GBN;

    // Staging: A tile 128 rows x 16 slots(16B) = 2048 slots = 4 rounds x 512;
    // B tile 64 x 16 = 1024 slots = 2 rounds. Linear LDS dest; global source
    // slot pre-swizzled slot' = slot ^ (row&15) (involution, matches ds_read).
    const unsigned short* gA[4];
    #pragma unroll
    for (int j = 0; j < 4; ++j) {
        const int slot = j * 512 + tid;
        const int r  = slot >> 4;
        const int sl = (slot & 15) ^ (r & 15);
        gA[j] = A + (size_t)(bm + r) * KC + sl * 8;
    }
    const unsigned short* gB[2];
    #pragma unroll
    for (int j = 0; j < 2; ++j) {
        const int slot = j * 512 + tid;
        const int r  = slot >> 4;
        const int sl = (slot & 15) ^ (r & 15);
        gB[j] = B + (size_t)(bn + r) * KC + sl * 8;
    }

    f32x4 acc[2][2] = {};

    const int lr = l & 15;     // fragment row-within-16
    const int ls = l >> 4;     // k-slot (8 bf16 each)
    int offA[2][4], offB[2][4];
    #pragma unroll
    for (int mi = 0; mi < 2; ++mi) {
        const int r = wr * 32 + mi * 16 + lr;
        #pragma unroll
        for (int ks = 0; ks < 4; ++ks)
            offA[mi][ks] = r * 128 + (((ks * 4 + ls) ^ (r & 15)) * 8);
    }
    #pragma unroll
    for (int ni = 0; ni < 2; ++ni) {
        const int r = wc * 32 + ni * 16 + lr;
        #pragma unroll
        for (int ks = 0; ks < 4; ++ks)
            offB[ni][ks] = r * 128 + (((ks * 4 + ls) ^ (r & 15)) * 8);
    }

    // prologue: stage tiles 0,1 (12 loads in flight per thread)
    STAGE(0, 0);
    STAGE(1, 1);

    #pragma unroll
    for (int kt = 0; kt < NT; ++kt) {
        // (a) tile kt resident; tile kt+1's 6 loads stay in flight
        if (kt < NT - 1) asm volatile("s_waitcnt vmcnt(6)" ::: "memory");
        else             asm volatile("s_waitcnt vmcnt(0)" ::: "memory");
        // (b) all waves: tile kt loaded everywhere, compute(kt-1) done
        __builtin_amdgcn_s_barrier();
        // (c) prefetch tile kt+2 (overwrites buf[(kt-1)%3], safe post-barrier)
        if (kt + 2 < NT) STAGE(kt + 2, (kt + 2) % 3);

        // (d) compute on buf kt%3: 16 MFMA per wave
        const int cb = kt % 3;
        bf16x8 af[2][4], bfv[2][4];
        #pragma unroll
        for (int mi = 0; mi < 2; ++mi)
            #pragma unroll
            for (int ks = 0; ks < 4; ++ks)
                af[mi][ks] = *(const bf16x8*)&As[cb][offA[mi][ks]];
        #pragma unroll
        for (int ni = 0; ni < 2; ++ni)
            #pragma unroll
            for (int ks = 0; ks < 4; ++ks)
                bfv[ni][ks] = *(const bf16x8*)&Bs[cb][offB[ni][ks]];

        #pragma unroll
        for (int mi = 0; mi < 2; ++mi)
            #pragma unroll
            for (int ni = 0; ni < 2; ++ni)
                #pragma unroll
                for (int ks = 0; ks < 4; ++ks)
                    acc[mi][ni] = __builtin_amdgcn_mfma_f32_16x16x32_bf16(af[mi][ks], bfv[ni][ks], acc[mi][ni], 0, 0, 0);
    }

    // C/D layout (m89): col = lane&15, row = (lane>>4)*4 + j
    #pragma unroll
    for (int mi = 0; mi < 2; ++mi) {
        const int row0 = bm + wr * 32 + mi * 16 + ls * 4;
        #pragma unroll
        for (int ni = 0; ni < 2; ++ni) {
            const int col = bn + wc * 32 + ni * 16 + lr;
            const float bv = bias ? bias[col] : 0.0f;
            #pragma unroll
            for (int j = 0; j < 4; ++j) {
                const float v = acc[mi][ni][j] + bv;
                if (OUT_BF16)
                    ((unsigned short*)Cout)[(size_t)(row0 + j) * N + col] = f2bf(v);
                else
                    ((float*)Cout)[(size_t)(row0 + j) * N + col] = v;
            }
        }
    }
}

// ---------------------------------------------------------------------------
// Fused softmax + rolling dynamic conv (proven R9 version).
// Block = (4 consecutive t, one b), 64 threads (1 wave).
// ---------------------------------------------------------------------------
__global__ __launch_bounds__(64) void dynconv_fused(const unsigned short* __restrict__ hb,
                                                    const unsigned short* __restrict__ lgb,
                                                    unsigned short* __restrict__ cvb) {
    __shared__ float w_s[64][33];

    const int bid = blockIdx.x;
    const int u   = (bid & 7) * 256 + (bid >> 3);   // 2048 % 8 == 0, bijective
    const int tg  = u >> 2;
    const int b   = u & 3;
    const int t0  = tg * 4;
    const int tid = threadIdx.x;

    {
        const int dt = tid >> 4, hd = tid & 15;
        const unsigned short* lp = lgb + (size_t)((t0 + dt) * BB + b) * NPAD + hd * KK;
        float e[KK];
        float mx = -1e30f;
        #pragma unroll
        for (int k = 0; k < KK; ++k) { e[k] = bf2f(lp[k]); mx = fmaxf(mx, e[k]); }
        float sm = 0.f;
        #pragma unroll
        for (int k = 0; k < KK; ++k) { e[k] = __expf(e[k] - mx); sm += e[k]; }
        const float inv = 1.f / sm;
        #pragma unroll
        for (int k = 0; k < KK; ++k) w_s[tid][k] = e[k] * inv;
    }
    __syncthreads();

    const int c0 = tid * 8;
    const int hd = tid >> 2;
    float acc[4][8] = {};
    #pragma unroll
    for (int j = 0; j < 34; ++j) {
        const int tt = t0 - PP + j;
        if ((unsigned)tt >= TT) continue;
        const ushort8 hv = *(const ushort8*)&hb[(size_t)((tt * BB + b) * CC) + c0];
        float hf[8];
        #pragma unroll
        for (int cc = 0; cc < 8; ++cc) hf[cc] = bf2f(hv[cc]);
        #pragma unroll
        for (int dt = 0; dt < 4; ++dt) {
            const int k = j - dt;
            if (k < 0 || k >= KK) continue;
            const float wk = w_s[dt * 16 + hd][k];
            #pragma unroll
            for (int cc = 0; cc < 8; ++cc) acc[dt][cc] = fmaf(hf[cc], wk, acc[dt][cc]);
        }
    }
    #pragma unroll
    for (int dt = 0; dt < 4; ++dt) {
        ushort8 o;
        #pragma unroll
        for (int cc = 0; cc < 8; ++cc) o[cc] = f2bf(acc[dt][cc]);
        *(ushort8*)&cvb[(size_t)(((t0 + dt) * BB + b) * CC) + c0] = o;
    }
}

extern "C" void kernel_launch(void* const* d_in, const int* in_sizes, int n_in,
                              void* d_out, int out_size, void* d_ws, size_t ws_size,
                              hipStream_t stream) {
    const float* x  = (const float*)d_in[0];
    const float* W1 = (const float*)d_in[1];
    const float* b1 = (const float*)d_in[2];
    const float* Wl = (const float*)d_in[3];
    const float* W2 = (const float*)d_in[4];
    const float* b2 = (const float*)d_in[5];
    float* out = (float*)d_out;

    // workspace layout (all bf16 except out)
    unsigned short* xb  = (unsigned short*)d_ws;             // 8 MB
    unsigned short* hb  = xb  + (size_t)MM * CC;             // 8 MB
    unsigned short* cvb = hb  + (size_t)MM * CC;             // 8 MB
    unsigned short* W1b = cvb + (size_t)MM * CC;             // 0.5 MB
    unsigned short* Wlb = W1b + (size_t)CC * CC;             // 0.5 MB (padded)
    unsigned short* W2b = Wlb + (size_t)NPAD * CC;           // 0.5 MB
    unsigned short* lgb = W2b + (size_t)CC * CC;             // 8 MB bf16 logits

    // single cast dispatch (x + all weights)
    cast_all<<<4096 + 768, 256, 0, stream>>>(x, W1, Wl, W2, xb, W1b, Wlb, W2b);

    const int nblk = (MM / GBM) * (CC / GBN);   // 64 * 8 = 512

    // 1) h = x @ W1^T + b1   (bf16 out)
    gemm_nt_mfma<true><<<nblk, 512, 0, stream>>>(xb, W1b, b1, hb, CC, CC / GBN);
    // 2) logits = h @ Wl^T   (bf16 out, padded N)
    gemm_nt_mfma<true><<<nblk, 512, 0, stream>>>(hb, Wlb, nullptr, lgb, NPAD, NPAD / GBN);
    // 3+4) fused softmax + rolling dynamic conv (bf16 out)
    dynconv_fused<<<TT * BB / 4, 64, 0, stream>>>(hb, lgb, cvb);
    // 5) out = cv @ W2^T + b2  (fp32 out)
    gemm_nt_mfma<false><<<nblk, 512, 0, stream>>>(cvb, W2b, b2, out, CC, CC / GBN);
}

// Round 19
// 52.467 us; speedup vs baseline: 1.0693x; 1.0693x over previous
//
#include <hip/hip_runtime.h>
#include <hip/hip_bf16.h>

// Problem constants
#define TT 2048
#define BB 4
#define CC 512
#define HH 16
#define KK 31
#define PP 15
#define MM (TT*BB)      // 8192 rows
#define NPAD 512        // HK=496 padded to 512 (pad rows of Wl are zero)

typedef __bf16 bf16x8 __attribute__((ext_vector_type(8)));
typedef float f32x4 __attribute__((ext_vector_type(4)));
typedef unsigned short ushort8 __attribute__((ext_vector_type(8)));
typedef unsigned short ushort4v __attribute__((ext_vector_type(4)));

__device__ __forceinline__ float bf2f(unsigned short u) {
    return __uint_as_float(((unsigned int)u) << 16);
}
__device__ __forceinline__ unsigned short f2bf(float f) {
    unsigned int x = __float_as_uint(f);
    x += 0x7fffu + ((x >> 16) & 1u);
    return (unsigned short)(x >> 16);
}

// ---------------------------------------------------------------------------
// single cast dispatch: blocks 0..4095 cast x (1024 elems each);
// blocks 4096..4863 cast W1/Wl/W2 (Wl zero-padded to 512 rows).
// ---------------------------------------------------------------------------
__global__ __launch_bounds__(256) void cast_all(const float* __restrict__ x,
                                                const float* __restrict__ W1,
                                                const float* __restrict__ Wl,
                                                const float* __restrict__ W2,
                                                unsigned short* __restrict__ xb,
                                                unsigned short* __restrict__ W1b,
                                                unsigned short* __restrict__ Wlb,
                                                unsigned short* __restrict__ W2b) {
    const int b = blockIdx.x;
    if (b < 4096) {
        const int i = b * 1024 + threadIdx.x * 4;
        const float4 v = *(const float4*)&x[i];
        ushort4v o = { f2bf(v.x), f2bf(v.y), f2bf(v.z), f2bf(v.w) };
        *(ushort4v*)&xb[i] = o;
        return;
    }
    const int bb = b - 4096;                 // 0..767
    const int i = (bb & 255) * 1024 + threadIdx.x * 4;
    const float* src;
    unsigned short* dst;
    int n_src = 262144;
    if (bb < 256)      { src = W1; dst = W1b; }
    else if (bb < 512) { src = Wl; dst = Wlb; n_src = HH * KK * CC; }
    else               { src = W2; dst = W2b; }
    ushort4v o = {0, 0, 0, 0};
    if (i < n_src) {
        const float4 v = *(const float4*)&src[i];
        o[0] = f2bf(v.x); o[1] = f2bf(v.y); o[2] = f2bf(v.z); o[3] = f2bf(v.w);
    }
    *(ushort4v*)&dst[i] = o;
}

// ---------------------------------------------------------------------------
// bf16 MFMA GEMM-NT, 3-stage counted-vmcnt pipeline, 8 waves (R13 config =
// proven champion, 50.36 us total): C[m,n] = sum_k A[m,k]*B[n,k] (+bias[n]).
// K fixed 512 (NT=8 x BK=64). 128x64 tile, 512 thr = 8 waves (4m x 2n),
// wave-tile 32x32 (2x2 fragments, 8 MFMA + 8 ds_read_b128 per K-step).
// LDS 3*(16+8)=72 KB -> 2 blocks/CU -> 16 waves/CU = 4 waves/SIMD.
// Per iter kt: {vmcnt(3); s_barrier; STAGE(kt+2); compute buf kt%3}.
// STAGE = 3 loads/thread (2 A rounds + 1 B round). Swizzle slot^=(row&7).
// ---------------------------------------------------------------------------
#define GBM 128
#define GBN 64
#define GBK 64
#define KC  512
#define NT  8

#define STAGE(kt, buf)                                                                             \
    do {                                                                                           \
        const int k0_ = (kt) * GBK;                                                                \
        _Pragma("unroll")                                                                          \
        for (int j = 0; j < 2; ++j)                                                                \
            __builtin_amdgcn_global_load_lds(                                                      \
                (const __attribute__((address_space(1))) void*)(gA[j] + k0_),                      \
                (__attribute__((address_space(3))) void*)(&As[buf][0] + (j * 512 + wv * 64) * 8),  \
                16, 0, 0);                                                                         \
        __builtin_amdgcn_global_load_lds(                                                          \
            (const __attribute__((address_space(1))) void*)(gB0 + k0_),                            \
            (__attribute__((address_space(3))) void*)(&Bs[buf][0] + wv * 64 * 8),                  \
            16, 0, 0);                                                                             \
    } while (0)

template<bool OUT_BF16>
__global__ __launch_bounds__(512, 4) void gemm_nt_mfma(const unsigned short* __restrict__ A,
                                                       const unsigned short* __restrict__ B,
                                                       const float* __restrict__ bias,
                                                       void* __restrict__ Cout,
                                                       int N, int nn) {
    __shared__ short As[3][GBM * GBK];   // 3 x 16 KB
    __shared__ short Bs[3][GBN * GBK];   // 3 x 8 KB

    const int tid = threadIdx.x;
    const int l   = tid & 63;
    const int wv  = tid >> 6;      // wave 0..7
    const int wr  = wv >> 1;       // wave row (0..3) -> 32 rows each
    const int wc  = wv & 1;        // wave col (0..1) -> 32 cols each

    // chunked XCD swizzle; consecutive s share A panel in the XCD's L2
    const int s  = (blockIdx.x & 7) * (gridDim.x >> 3) + (blockIdx.x >> 3);
    const int bm = (s / nn) * GBM;
    const int bn = (s % nn) * GBN;

    // Staging: A tile 128 rows x 8 slots(16B) = 1024 slots = 2 rounds x 512thr;
    // B tile 64 x 8 = 512 slots = 1 round. Linear LDS dest; source slot
    // pre-swizzled slot' = slot ^ (row&7) (involution, matches ds_read).
    const unsigned short* gA[2];
    #pragma unroll
    for (int j = 0; j < 2; ++j) {
        const int slot = j * 512 + tid;
        const int r  = slot >> 3;
        const int sl = (slot & 7) ^ (r & 7);
        gA[j] = A + (size_t)(bm + r) * KC + sl * 8;
    }
    const int rB  = tid >> 3;
    const int slB = (tid & 7) ^ (rB & 7);
    const unsigned short* gB0 = B + (size_t)(bn + rB) * KC + slB * 8;

    f32x4 acc[2][2] = {};

    const int lr = l & 15;     // fragment row-within-16
    const int ls = l >> 4;     // k-slot (8 bf16 each)
    int offA[2][2], offB[2][2];
    #pragma unroll
    for (int mi = 0; mi < 2; ++mi) {
        const int r = wr * 32 + mi * 16 + lr;
        #pragma unroll
        for (int ks = 0; ks < 2; ++ks)
            offA[mi][ks] = r * 64 + (((ks * 4 + ls) ^ (r & 7)) * 8);
    }
    #pragma unroll
    for (int ni = 0; ni < 2; ++ni) {
        const int r = wc * 32 + ni * 16 + lr;
        #pragma unroll
        for (int ks = 0; ks < 2; ++ks)
            offB[ni][ks] = r * 64 + (((ks * 4 + ls) ^ (r & 7)) * 8);
    }

    // prologue: stage tiles 0,1 (6 loads in flight per thread-slot)
    STAGE(0, 0);
    STAGE(1, 1);

    #pragma unroll
    for (int kt = 0; kt < NT; ++kt) {
        // (a) tile kt resident; tile kt+1's 3 loads stay in flight
        if (kt < NT - 1) asm volatile("s_waitcnt vmcnt(3)" ::: "memory");
        else             asm volatile("s_waitcnt vmcnt(0)" ::: "memory");
        // (b) all waves: tile kt loaded everywhere, compute(kt-1) done
        __builtin_amdgcn_s_barrier();
        // (c) prefetch tile kt+2 (overwrites buf[(kt-1)%3], safe post-barrier)
        if (kt + 2 < NT) STAGE(kt + 2, (kt + 2) % 3);

        // (d) compute on buf kt%3
        const int cb = kt % 3;
        bf16x8 af[2][2], bfv[2][2];
        #pragma unroll
        for (int mi = 0; mi < 2; ++mi)
            #pragma unroll
            for (int ks = 0; ks < 2; ++ks)
                af[mi][ks] = *(const bf16x8*)&As[cb][offA[mi][ks]];
        #pragma unroll
        for (int ni = 0; ni < 2; ++ni)
            #pragma unroll
            for (int ks = 0; ks < 2; ++ks)
                bfv[ni][ks] = *(const bf16x8*)&Bs[cb][offB[ni][ks]];

        #pragma unroll
        for (int mi = 0; mi < 2; ++mi)
            #pragma unroll
            for (int ni = 0; ni < 2; ++ni)
                #pragma unroll
                for (int ks = 0; ks < 2; ++ks)
                    acc[mi][ni] = __builtin_amdgcn_mfma_f32_16x16x32_bf16(af[mi][ks], bfv[ni][ks], acc[mi][ni], 0, 0, 0);
    }

    // C/D layout (m89): col = lane&15, row = (lane>>4)*4 + j
    #pragma unroll
    for (int mi = 0; mi < 2; ++mi) {
        const int row0 = bm + wr * 32 + mi * 16 + ls * 4;
        #pragma unroll
        for (int ni = 0; ni < 2; ++ni) {
            const int col = bn + wc * 32 + ni * 16 + lr;
            const float bv = bias ? bias[col] : 0.0f;
            #pragma unroll
            for (int j = 0; j < 4; ++j) {
                const float v = acc[mi][ni][j] + bv;
                if (OUT_BF16)
                    ((unsigned short*)Cout)[(size_t)(row0 + j) * N + col] = f2bf(v);
                else
                    ((float*)Cout)[(size_t)(row0 + j) * N + col] = v;
            }
        }
    }
}

// ---------------------------------------------------------------------------
// Fused softmax + rolling dynamic conv, 8-deep:
// Block = (8 consecutive t, one b), 64 threads (1 wave). 1024 blocks.
// Phase 1: 128 softmax rows (8t x 16 heads), 2 rows per thread; logits read
//          as 4x ushort8 (32 elems, last discarded; hd*31+32 <= 496 in-bounds).
// Phase 2: thread = 8-channel group; rolls once over the 38-row union window,
//          accumulating 8 outputs in regs -> 4.75 row-loads/output (was 8.5).
// ---------------------------------------------------------------------------
__global__ __launch_bounds__(64) void dynconv_fused(const unsigned short* __restrict__ hb,
                                                    const unsigned short* __restrict__ lgb,
                                                    unsigned short* __restrict__ cvb) {
    __shared__ float w_s[128][33];   // 16.9 KB

    const int bid = blockIdx.x;
    const int u   = (bid & 7) * 128 + (bid >> 3);   // 1024 % 8 == 0, bijective
    const int tg  = u >> 2;
    const int b   = u & 3;
    const int t0  = tg * 8;
    const int tid = threadIdx.x;

    // ---- Phase 1: softmax over K=31; 2 rows per thread ----
    #pragma unroll
    for (int rr2 = 0; rr2 < 2; ++rr2) {
        const int rr = tid * 2 + rr2;        // 0..127: dt = rr>>4, head = rr&15
        const int dt = rr >> 4, hd = rr & 15;
        const unsigned short* lp = lgb + (size_t)((t0 + dt) * BB + b) * NPAD + hd * KK;
        float e[32];
        #pragma unroll
        for (int v8 = 0; v8 < 4; ++v8) {
            const ushort8 lv = *(const ushort8*)&lp[v8 * 8];
            #pragma unroll
            for (int j = 0; j < 8; ++j) e[v8 * 8 + j] = bf2f(lv[j]);
        }
        float mx = -1e30f;
        #pragma unroll
        for (int k = 0; k < KK; ++k) mx = fmaxf(mx, e[k]);
        float sm = 0.f;
        #pragma unroll
        for (int k = 0; k < KK; ++k) { e[k] = __expf(e[k] - mx); sm += e[k]; }
        const float inv = 1.f / sm;
        #pragma unroll
        for (int k = 0; k < KK; ++k) w_s[rr][k] = e[k] * inv;
    }
    __syncthreads();

    // ---- Phase 2: rolling conv, 8 outputs per thread ----
    const int c0 = tid * 8;
    const int hd = tid >> 2;      // head = c0 >> 5
    float acc[8][8] = {};
    #pragma unroll
    for (int j = 0; j < 38; ++j) {             // tt = t0 - 15 + j
        const int tt = t0 - PP + j;
        if ((unsigned)tt >= TT) continue;
        const ushort8 hv = *(const ushort8*)&hb[(size_t)((tt * BB + b) * CC) + c0];
        float hf[8];
        #pragma unroll
        for (int cc = 0; cc < 8; ++cc) hf[cc] = bf2f(hv[cc]);
        #pragma unroll
        for (int dt = 0; dt < 8; ++dt) {
            const int k = j - dt;              // tap index for output t0+dt
            if ((unsigned)k >= KK) continue;
            const float wk = w_s[dt * 16 + hd][k];
            #pragma unroll
            for (int cc = 0; cc < 8; ++cc) acc[dt][cc] = fmaf(hf[cc], wk, acc[dt][cc]);
        }
    }
    #pragma unroll
    for (int dt = 0; dt < 8; ++dt) {
        ushort8 o;
        #pragma unroll
        for (int cc = 0; cc < 8; ++cc) o[cc] = f2bf(acc[dt][cc]);
        *(ushort8*)&cvb[(size_t)(((t0 + dt) * BB + b) * CC) + c0] = o;
    }
}

extern "C" void kernel_launch(void* const* d_in, const int* in_sizes, int n_in,
                              void* d_out, int out_size, void* d_ws, size_t ws_size,
                              hipStream_t stream) {
    const float* x  = (const float*)d_in[0];
    const float* W1 = (const float*)d_in[1];
    const float* b1 = (const float*)d_in[2];
    const float* Wl = (const float*)d_in[3];
    const float* W2 = (const float*)d_in[4];
    const float* b2 = (const float*)d_in[5];
    float* out = (float*)d_out;

    // workspace layout (all bf16 except out)
    unsigned short* xb  = (unsigned short*)d_ws;             // 8 MB
    unsigned short* hb  = xb  + (size_t)MM * CC;             // 8 MB
    unsigned short* cvb = hb  + (size_t)MM * CC;             // 8 MB
    unsigned short* W1b = cvb + (size_t)MM * CC;             // 0.5 MB
    unsigned short* Wlb = W1b + (size_t)CC * CC;             // 0.5 MB (padded)
    unsigned short* W2b = Wlb + (size_t)NPAD * CC;           // 0.5 MB
    unsigned short* lgb = W2b + (size_t)CC * CC;             // 8 MB bf16 logits

    // single cast dispatch (x + all weights)
    cast_all<<<4096 + 768, 256, 0, stream>>>(x, W1, Wl, W2, xb, W1b, Wlb, W2b);

    const int nblk = (MM / GBM) * (CC / GBN);   // 64 * 8 = 512

    // 1) h = x @ W1^T + b1   (bf16 out)
    gemm_nt_mfma<true><<<nblk, 512, 0, stream>>>(xb, W1b, b1, hb, CC, CC / GBN);
    // 2) logits = h @ Wl^T   (bf16 out, padded N)
    gemm_nt_mfma<true><<<nblk, 512, 0, stream>>>(hb, Wlb, nullptr, lgb, NPAD, NPAD / GBN);
    // 3+4) fused softmax + rolling dynamic conv, 8-deep (bf16 out)
    dynconv_fused<<<TT * BB / 8, 64, 0, stream>>>(hb, lgb, cvb);
    // 5) out = cv @ W2^T + b2  (fp32 out)
    gemm_nt_mfma<false><<<nblk, 512, 0, stream>>>(cvb, W2b, b2, out, CC, CC / GBN);
}

// Round 20
// 50.499 us; speedup vs baseline: 1.1110x; 1.0390x over previous
//
#include <hip/hip_runtime.h>
#include <hip/hip_bf16.h>

// Problem constants
#define TT 2048
#define BB 4
#define CC 512
#define HH 16
#define KK 31
#define PP 15
#define MM (TT*BB)      // 8192 rows
#define NPAD 512        // HK=496 padded to 512 (pad rows of Wl are zero)

typedef __bf16 bf16x8 __attribute__((ext_vector_type(8)));
typedef float f32x4 __attribute__((ext_vector_type(4)));
typedef unsigned short ushort8 __attribute__((ext_vector_type(8)));
typedef unsigned short ushort4v __attribute__((ext_vector_type(4)));

__device__ __forceinline__ float bf2f(unsigned short u) {
    return __uint_as_float(((unsigned int)u) << 16);
}
__device__ __forceinline__ unsigned short f2bf(float f) {
    unsigned int x = __float_as_uint(f);
    x += 0x7fffu + ((x >> 16) & 1u);
    return (unsigned short)(x >> 16);
}

// ---------------------------------------------------------------------------
// single cast dispatch: blocks 0..4095 cast x (1024 elems each);
// blocks 4096..4863 cast W1/Wl/W2 (Wl zero-padded to 512 rows).
// ---------------------------------------------------------------------------
__global__ __launch_bounds__(256) void cast_all(const float* __restrict__ x,
                                                const float* __restrict__ W1,
                                                const float* __restrict__ Wl,
                                                const float* __restrict__ W2,
                                                unsigned short* __restrict__ xb,
                                                unsigned short* __restrict__ W1b,
                                                unsigned short* __restrict__ Wlb,
                                                unsigned short* __restrict__ W2b) {
    const int b = blockIdx.x;
    if (b < 4096) {
        const int i = b * 1024 + threadIdx.x * 4;
        const float4 v = *(const float4*)&x[i];
        ushort4v o = { f2bf(v.x), f2bf(v.y), f2bf(v.z), f2bf(v.w) };
        *(ushort4v*)&xb[i] = o;
        return;
    }
    const int bb = b - 4096;                 // 0..767
    const int i = (bb & 255) * 1024 + threadIdx.x * 4;
    const float* src;
    unsigned short* dst;
    int n_src = 262144;
    if (bb < 256)      { src = W1; dst = W1b; }
    else if (bb < 512) { src = Wl; dst = Wlb; n_src = HH * KK * CC; }
    else               { src = W2; dst = W2b; }
    ushort4v o = {0, 0, 0, 0};
    if (i < n_src) {
        const float4 v = *(const float4*)&src[i];
        o[0] = f2bf(v.x); o[1] = f2bf(v.y); o[2] = f2bf(v.z); o[3] = f2bf(v.w);
    }
    *(ushort4v*)&dst[i] = o;
}

// ---------------------------------------------------------------------------
// bf16 MFMA GEMM-NT, 3-stage counted-vmcnt pipeline, 8 waves (R13 config =
// proven champion, 50.36 us total): C[m,n] = sum_k A[m,k]*B[n,k] (+bias[n]).
// K fixed 512 (NT=8 x BK=64). 128x64 tile, 512 thr = 8 waves (4m x 2n),
// wave-tile 32x32 (2x2 fragments, 8 MFMA + 8 ds_read_b128 per K-step).
// LDS 3*(16+8)=72 KB -> 2 blocks/CU -> 16 waves/CU = 4 waves/SIMD.
// Per iter kt: {vmcnt(3); s_barrier; STAGE(kt+2); compute buf kt%3}.
// STAGE = 3 loads/thread (2 A rounds + 1 B round). Swizzle slot^=(row&7).
// ---------------------------------------------------------------------------
#define GBM 128
#define GBN 64
#define GBK 64
#define KC  512
#define NT  8

#define STAGE(kt, buf)                                                                             \
    do {                                                                                           \
        const int k0_ = (kt) * GBK;                                                                \
        _Pragma("unroll")                                                                          \
        for (int j = 0; j < 2; ++j)                                                                \
            __builtin_amdgcn_global_load_lds(                                                      \
                (const __attribute__((address_space(1))) void*)(gA[j] + k0_),                      \
                (__attribute__((address_space(3))) void*)(&As[buf][0] + (j * 512 + wv * 64) * 8),  \
                16, 0, 0);                                                                         \
        __builtin_amdgcn_global_load_lds(                                                          \
            (const __attribute__((address_space(1))) void*)(gB0 + k0_),                            \
            (__attribute__((address_space(3))) void*)(&Bs[buf][0] + wv * 64 * 8),                  \
            16, 0, 0);                                                                             \
    } while (0)

template<bool OUT_BF16>
__global__ __launch_bounds__(512, 4) void gemm_nt_mfma(const unsigned short* __restrict__ A,
                                                       const unsigned short* __restrict__ B,
                                                       const float* __restrict__ bias,
                                                       void* __restrict__ Cout,
                                                       int N, int nn) {
    __shared__ short As[3][GBM * GBK];   // 3 x 16 KB
    __shared__ short Bs[3][GBN * GBK];   // 3 x 8 KB

    const int tid = threadIdx.x;
    const int l   = tid & 63;
    const int wv  = tid >> 6;      // wave 0..7
    const int wr  = wv >> 1;       // wave row (0..3) -> 32 rows each
    const int wc  = wv & 1;        // wave col (0..1) -> 32 cols each

    // chunked XCD swizzle; consecutive s share A panel in the XCD's L2
    const int s  = (blockIdx.x & 7) * (gridDim.x >> 3) + (blockIdx.x >> 3);
    const int bm = (s / nn) * GBM;
    const int bn = (s % nn) * GBN;

    // Staging: A tile 128 rows x 8 slots(16B) = 1024 slots = 2 rounds x 512thr;
    // B tile 64 x 8 = 512 slots = 1 round. Linear LDS dest; source slot
    // pre-swizzled slot' = slot ^ (row&7) (involution, matches ds_read).
    const unsigned short* gA[2];
    #pragma unroll
    for (int j = 0; j < 2; ++j) {
        const int slot = j * 512 + tid;
        const int r  = slot >> 3;
        const int sl = (slot & 7) ^ (r & 7);
        gA[j] = A + (size_t)(bm + r) * KC + sl * 8;
    }
    const int rB  = tid >> 3;
    const int slB = (tid & 7) ^ (rB & 7);
    const unsigned short* gB0 = B + (size_t)(bn + rB) * KC + slB * 8;

    f32x4 acc[2][2] = {};

    const int lr = l & 15;     // fragment row-within-16
    const int ls = l >> 4;     // k-slot (8 bf16 each)
    int offA[2][2], offB[2][2];
    #pragma unroll
    for (int mi = 0; mi < 2; ++mi) {
        const int r = wr * 32 + mi * 16 + lr;
        #pragma unroll
        for (int ks = 0; ks < 2; ++ks)
            offA[mi][ks] = r * 64 + (((ks * 4 + ls) ^ (r & 7)) * 8);
    }
    #pragma unroll
    for (int ni = 0; ni < 2; ++ni) {
        const int r = wc * 32 + ni * 16 + lr;
        #pragma unroll
        for (int ks = 0; ks < 2; ++ks)
            offB[ni][ks] = r * 64 + (((ks * 4 + ls) ^ (r & 7)) * 8);
    }

    // prologue: stage tiles 0,1 (6 loads in flight per thread-slot)
    STAGE(0, 0);
    STAGE(1, 1);

    #pragma unroll
    for (int kt = 0; kt < NT; ++kt) {
        // (a) tile kt resident; tile kt+1's 3 loads stay in flight
        if (kt < NT - 1) asm volatile("s_waitcnt vmcnt(3)" ::: "memory");
        else             asm volatile("s_waitcnt vmcnt(0)" ::: "memory");
        // (b) all waves: tile kt loaded everywhere, compute(kt-1) done
        __builtin_amdgcn_s_barrier();
        // (c) prefetch tile kt+2 (overwrites buf[(kt-1)%3], safe post-barrier)
        if (kt + 2 < NT) STAGE(kt + 2, (kt + 2) % 3);

        // (d) compute on buf kt%3
        const int cb = kt % 3;
        bf16x8 af[2][2], bfv[2][2];
        #pragma unroll
        for (int mi = 0; mi < 2; ++mi)
            #pragma unroll
            for (int ks = 0; ks < 2; ++ks)
                af[mi][ks] = *(const bf16x8*)&As[cb][offA[mi][ks]];
        #pragma unroll
        for (int ni = 0; ni < 2; ++ni)
            #pragma unroll
            for (int ks = 0; ks < 2; ++ks)
                bfv[ni][ks] = *(const bf16x8*)&Bs[cb][offB[ni][ks]];

        #pragma unroll
        for (int mi = 0; mi < 2; ++mi)
            #pragma unroll
            for (int ni = 0; ni < 2; ++ni)
                #pragma unroll
                for (int ks = 0; ks < 2; ++ks)
                    acc[mi][ni] = __builtin_amdgcn_mfma_f32_16x16x32_bf16(af[mi][ks], bfv[ni][ks], acc[mi][ni], 0, 0, 0);
    }

    // C/D layout (m89): col = lane&15, row = (lane>>4)*4 + j
    #pragma unroll
    for (int mi = 0; mi < 2; ++mi) {
        const int row0 = bm + wr * 32 + mi * 16 + ls * 4;
        #pragma unroll
        for (int ni = 0; ni < 2; ++ni) {
            const int col = bn + wc * 32 + ni * 16 + lr;
            const float bv = bias ? bias[col] : 0.0f;
            #pragma unroll
            for (int j = 0; j < 4; ++j) {
                const float v = acc[mi][ni][j] + bv;
                if (OUT_BF16)
                    ((unsigned short*)Cout)[(size_t)(row0 + j) * N + col] = f2bf(v);
                else
                    ((float*)Cout)[(size_t)(row0 + j) * N + col] = v;
            }
        }
    }
}

// ---------------------------------------------------------------------------
// Fused softmax + rolling dynamic conv (proven R9/R13 4-deep version; the
// only change vs R13 is vectorized logit loads in phase 1).
// Block = (4 consecutive t, one b), 64 threads (1 wave). 2048 blocks.
// ---------------------------------------------------------------------------
__global__ __launch_bounds__(64) void dynconv_fused(const unsigned short* __restrict__ hb,
                                                    const unsigned short* __restrict__ lgb,
                                                    unsigned short* __restrict__ cvb) {
    __shared__ float w_s[64][33];

    const int bid = blockIdx.x;
    const int u   = (bid & 7) * 256 + (bid >> 3);   // 2048 % 8 == 0, bijective
    const int tg  = u >> 2;
    const int b   = u & 3;
    const int t0  = tg * 4;
    const int tid = threadIdx.x;

    // ---- Phase 1: softmax over K=31; lane = (dt, head); vectorized loads
    //      (4x ushort8 = 32 elems; elem 32 in-bounds: hd*31+32 <= 497 < 512) ----
    {
        const int dt = tid >> 4, hd = tid & 15;
        const unsigned short* lp = lgb + (size_t)((t0 + dt) * BB + b) * NPAD + hd * KK;
        float e[32];
        #pragma unroll
        for (int v8 = 0; v8 < 4; ++v8) {
            const ushort8 lv = *(const ushort8*)&lp[v8 * 8];
            #pragma unroll
            for (int j = 0; j < 8; ++j) e[v8 * 8 + j] = bf2f(lv[j]);
        }
        float mx = -1e30f;
        #pragma unroll
        for (int k = 0; k < KK; ++k) mx = fmaxf(mx, e[k]);
        float sm = 0.f;
        #pragma unroll
        for (int k = 0; k < KK; ++k) { e[k] = __expf(e[k] - mx); sm += e[k]; }
        const float inv = 1.f / sm;
        #pragma unroll
        for (int k = 0; k < KK; ++k) w_s[tid][k] = e[k] * inv;
    }
    __syncthreads();

    // ---- Phase 2: rolling conv; thread = channel-group (8 ch), 4 outputs ----
    const int c0 = tid * 8;
    const int hd = tid >> 2;      // head = c0 >> 5
    float acc[4][8] = {};
    #pragma unroll
    for (int j = 0; j < 34; ++j) {             // tt = t0 - 15 + j
        const int tt = t0 - PP + j;
        if ((unsigned)tt >= TT) continue;
        const ushort8 hv = *(const ushort8*)&hb[(size_t)((tt * BB + b) * CC) + c0];
        float hf[8];
        #pragma unroll
        for (int cc = 0; cc < 8; ++cc) hf[cc] = bf2f(hv[cc]);
        #pragma unroll
        for (int dt = 0; dt < 4; ++dt) {
            const int k = j - dt;              // tap index for output t0+dt
            if ((unsigned)k >= KK) continue;
            const float wk = w_s[dt * 16 + hd][k];
            #pragma unroll
            for (int cc = 0; cc < 8; ++cc) acc[dt][cc] = fmaf(hf[cc], wk, acc[dt][cc]);
        }
    }
    #pragma unroll
    for (int dt = 0; dt < 4; ++dt) {
        ushort8 o;
        #pragma unroll
        for (int cc = 0; cc < 8; ++cc) o[cc] = f2bf(acc[dt][cc]);
        *(ushort8*)&cvb[(size_t)(((t0 + dt) * BB + b) * CC) + c0] = o;
    }
}

extern "C" void kernel_launch(void* const* d_in, const int* in_sizes, int n_in,
                              void* d_out, int out_size, void* d_ws, size_t ws_size,
                              hipStream_t stream) {
    const float* x  = (const float*)d_in[0];
    const float* W1 = (const float*)d_in[1];
    const float* b1 = (const float*)d_in[2];
    const float* Wl = (const float*)d_in[3];
    const float* W2 = (const float*)d_in[4];
    const float* b2 = (const float*)d_in[5];
    float* out = (float*)d_out;

    // workspace layout (all bf16 except out)
    unsigned short* xb  = (unsigned short*)d_ws;             // 8 MB
    unsigned short* hb  = xb  + (size_t)MM * CC;             // 8 MB
    unsigned short* cvb = hb  + (size_t)MM * CC;             // 8 MB
    unsigned short* W1b = cvb + (size_t)MM * CC;             // 0.5 MB
    unsigned short* Wlb = W1b + (size_t)CC * CC;             // 0.5 MB (padded)
    unsigned short* W2b = Wlb + (size_t)NPAD * CC;           // 0.5 MB
    unsigned short* lgb = W2b + (size_t)CC * CC;             // 8 MB bf16 logits

    // single cast dispatch (x + all weights)
    cast_all<<<4096 + 768, 256, 0, stream>>>(x, W1, Wl, W2, xb, W1b, Wlb, W2b);

    const int nblk = (MM / GBM) * (CC / GBN);   // 64 * 8 = 512

    // 1) h = x @ W1^T + b1   (bf16 out)
    gemm_nt_mfma<true><<<nblk, 512, 0, stream>>>(xb, W1b, b1, hb, CC, CC / GBN);
    // 2) logits = h @ Wl^T   (bf16 out, padded N)
    gemm_nt_mfma<true><<<nblk, 512, 0, stream>>>(hb, Wlb, nullptr, lgb, NPAD, NPAD / GBN);
    // 3+4) fused softmax + rolling dynamic conv (bf16 out)
    dynconv_fused<<<TT * BB / 4, 64, 0, stream>>>(hb, lgb, cvb);
    // 5) out = cv @ W2^T + b2  (fp32 out)
    gemm_nt_mfma<false><<<nblk, 512, 0, stream>>>(cvb, W2b, b2, out, CC, CC / GBN);
}